// Round 9
// baseline (82.370 us; speedup 1.0000x reference)
//
#include <hip/hip_runtime.h>

// FlowNetC fused: f1=conv3x3(x1,w), f2=conv3x3(x2,w),
// out[b,k,h,w] = mean_c f1[b,c,h,w]*f2[b,c,h+dy,w+dx], dy,dx in {-2,0,2}
// B=16,C=3,H=W=512,K=9. f32.
//
// R9 = R7 design, f1-from-global block rewritten ICE-safe (clamped
// unconditional loads + 0/1 mask multiply, win[3][6] filled by plain
// assignments -- the exact structural pattern R4-R6 compiled cleanly):
//  - f1 straight from GLOBAL x1 -> no x1 LDS staging, no f1 LDS reads,
//    2 barriers. f1 global loads overlap x2 global_load_lds staging.
//  - LDS 35.5KB (s_x2 + s_f2) -> 4 blocks/CU.
//  - scalar-pipe weights, 1/3 folded into f1, dwordx4 nontemporal stores,
//    XCD-contiguous swizzle.

#define HH 512
#define WW 512
#define TS 32
#define X2R 38              // TS+6 rows per channel
#define X2S 40              // stride words (10 chunks/row)
#define F2R 36              // TS+4
#define F2S 40
#define NC2 (3*X2R*(X2S/4)) // 1140 16B chunks
#define NFU (F2R*9)         // 324 f2 run-units

typedef const __attribute__((address_space(1))) void* gas_ptr;
typedef __attribute__((address_space(3))) void* las_ptr;
typedef float f32x4 __attribute__((ext_vector_type(4)));

__global__ __launch_bounds__(256)
void flownetc_fused_kernel(const float* __restrict__ x1,
                           const float* __restrict__ x2,
                           const float* __restrict__ cw,
                           float* __restrict__ out) {
  __shared__ __align__(16) float s_x2[3*X2R*X2S];   // 4560 w = 18.2KB
  __shared__ __align__(16) float s_f2[3*F2R*F2S];   // 4320 w = 17.3KB

  const int tid = threadIdx.x;
  // XCD-contiguous swizzle: 4096 blocks / 8 XCDs = 512 contiguous each
  const int bid = blockIdx.x;
  const int f   = (bid & 7) * 512 + (bid >> 3);
  const int ox0 = (f & 15) * TS;
  const int oy0 = ((f >> 4) & 15) * TS;
  const int bi  = f >> 8;

  const float* x2b = x2 + (size_t)bi * 3 * HH * WW;
  const float* x1b = x1 + (size_t)bi * 3 * HH * WW;

  // ---- async stage x2 [3][38][40] origin (oy0-3, ox0-3), 16B chunks ----
  for (int q = tid; q < NC2; q += 256) {
    const int colq = q % (X2S / 4);
    const int rp   = q / (X2S / 4);
    const int r    = rp % X2R;
    const int c    = rp / X2R;
    const int gy   = oy0 - 3 + r;
    const int gx0  = ox0 - 3 + colq * 4;
    const float* src = x2b + (size_t)(c * HH + gy) * WW + gx0;
    if ((unsigned)gy < HH && (unsigned)gx0 <= (WW - 4)) {
      __builtin_amdgcn_global_load_lds((gas_ptr)src,
          (las_ptr)(s_x2 + ((q & ~63) << 2)), 16, 0, 0);
    } else {
      const bool rowok = (unsigned)gy < HH;
      float4 v;
      v.x = (rowok && (unsigned)(gx0 + 0) < WW) ? src[0] : 0.f;
      v.y = (rowok && (unsigned)(gx0 + 1) < WW) ? src[1] : 0.f;
      v.z = (rowok && (unsigned)(gx0 + 2) < WW) ? src[2] : 0.f;
      v.w = (rowok && (unsigned)(gx0 + 3) < WW) ? src[3] : 0.f;
      *reinterpret_cast<float4*>(&s_x2[q * 4]) = v;
    }
  }

  // ---- f1 from global x1 (clamped loads + mask), overlaps staging ----
  const int py  = tid >> 3;          // 0..31
  const int px0 = (tid & 7) << 2;    // 0..28
  const int gx0 = ox0 + px0;
  const int lidx = (gx0 == 0)       ? 0      : gx0 - 1;   // clamped L addr
  const int ridx = (gx0 >= WW - 4)  ? WW - 1 : gx0 + 4;   // clamped R addr
  const float mLc = (gx0 > 0)      ? 1.f : 0.f;
  const float mRc = (gx0 < WW - 4) ? 1.f : 0.f;
  float f1r[3][4] = {};
  #pragma unroll
  for (int ci = 0; ci < 3; ++ci) {
    float win[3][6];
    #pragma unroll
    for (int ky = 0; ky < 3; ++ky) {
      const int gy  = oy0 + py - 1 + ky;
      const int gyc = gy < 0 ? 0 : (gy >= HH ? HH - 1 : gy);
      const float mrow = ((unsigned)gy < HH) ? 1.f : 0.f;
      const float* p = x1b + (size_t)(ci * HH + gyc) * WW;
      const float4 A = *reinterpret_cast<const float4*>(p + gx0);
      const float Lv = p[lidx];
      const float Rv = p[ridx];
      win[ky][0] = (mLc * mrow) * Lv;
      win[ky][1] = mrow * A.x;
      win[ky][2] = mrow * A.y;
      win[ky][3] = mrow * A.z;
      win[ky][4] = mrow * A.w;
      win[ky][5] = (mRc * mrow) * Rv;
    }
    #pragma unroll
    for (int co = 0; co < 3; ++co)
      #pragma unroll
      for (int ky = 0; ky < 3; ++ky)
        #pragma unroll
        for (int kx = 0; kx < 3; ++kx) {
          const float w = cw[((co * 3 + ci) * 3 + ky) * 3 + kx]; // SGPR
          #pragma unroll
          for (int j = 0; j < 4; ++j)
            f1r[co][j] += w * win[ky][j + kx];
        }
  }
  #pragma unroll
  for (int co = 0; co < 3; ++co)
    #pragma unroll
    for (int j = 0; j < 4; ++j)
      f1r[co][j] *= (1.f / 3.f);     // fold mean divisor
  __syncthreads();   // x2 staging complete (vmcnt+lgkm drained)

  // ---- f2 from s_x2 -> s_f2 directly; 324 units ----
  for (int u = tid; u < NFU; u += 256) {
    const int r    = u / 9;
    const int col0 = (u - r * 9) * 4;
    float acc[3][4] = {};
    #pragma unroll
    for (int ci = 0; ci < 3; ++ci) {
      float win[3][6];
      #pragma unroll
      for (int ky = 0; ky < 3; ++ky) {
        const float* base = &s_x2[(ci * X2R + r + ky) * X2S + col0];
        const float4 a  = *reinterpret_cast<const float4*>(base);
        const float2 b2 = *reinterpret_cast<const float2*>(base + 4);
        win[ky][0] = a.x; win[ky][1] = a.y; win[ky][2] = a.z; win[ky][3] = a.w;
        win[ky][4] = b2.x; win[ky][5] = b2.y;
      }
      #pragma unroll
      for (int co = 0; co < 3; ++co)
        #pragma unroll
        for (int ky = 0; ky < 3; ++ky)
          #pragma unroll
          for (int kx = 0; kx < 3; ++kx) {
            const float w = cw[((co * 3 + ci) * 3 + ky) * 3 + kx];
            #pragma unroll
            for (int j = 0; j < 4; ++j)
              acc[co][j] += w * win[ky][j + kx];
          }
    }
    // correlation zero-pads f2: zero outside the image
    const int gy = oy0 - 2 + r;
    #pragma unroll
    for (int j = 0; j < 4; ++j) {
      const int gx = ox0 - 2 + col0 + j;
      if (!((unsigned)gy < HH && (unsigned)gx < WW)) {
        acc[0][j] = 0.f; acc[1][j] = 0.f; acc[2][j] = 0.f;
      }
    }
    #pragma unroll
    for (int co = 0; co < 3; ++co)
      *reinterpret_cast<float4*>(&s_f2[(co * F2R + r) * F2S + col0]) =
          make_float4(acc[co][0], acc[co][1], acc[co][2], acc[co][3]);
  }
  __syncthreads();   // f2 tile ready

  // ---- correlation + nontemporal dwordx4 stores ----
  float* outp = out + ((size_t)bi * 9 * HH + (oy0 + py)) * WW + gx0;
  #pragma unroll
  for (int dyi = 0; dyi < 3; ++dyi) {
    float rv[3][8];
    #pragma unroll
    for (int c = 0; c < 3; ++c) {
      const float* base = &s_f2[(c * F2R + py + dyi * 2) * F2S + px0];
      const float4 a = *reinterpret_cast<const float4*>(base);
      const float4 b = *reinterpret_cast<const float4*>(base + 4);
      rv[c][0] = a.x; rv[c][1] = a.y; rv[c][2] = a.z; rv[c][3] = a.w;
      rv[c][4] = b.x; rv[c][5] = b.y; rv[c][6] = b.z; rv[c][7] = b.w;
    }
    #pragma unroll
    for (int dxi = 0; dxi < 3; ++dxi) {
      const int s = dxi * 2;
      f32x4 o;
      o.x = f1r[0][0]*rv[0][s+0] + f1r[1][0]*rv[1][s+0] + f1r[2][0]*rv[2][s+0];
      o.y = f1r[0][1]*rv[0][s+1] + f1r[1][1]*rv[1][s+1] + f1r[2][1]*rv[2][s+1];
      o.z = f1r[0][2]*rv[0][s+2] + f1r[1][2]*rv[1][s+2] + f1r[2][2]*rv[2][s+2];
      o.w = f1r[0][3]*rv[0][s+3] + f1r[1][3]*rv[1][s+3] + f1r[2][3]*rv[2][s+3];
      __builtin_nontemporal_store(o,
          reinterpret_cast<f32x4*>(outp + (size_t)(dyi * 3 + dxi) * HH * WW));
    }
  }
}

extern "C" void kernel_launch(void* const* d_in, const int* in_sizes, int n_in,
                              void* d_out, int out_size, void* d_ws, size_t ws_size,
                              hipStream_t stream) {
  const float* x1 = (const float*)d_in[0];
  const float* x2 = (const float*)d_in[1];
  const float* cw = (const float*)d_in[2];
  float* out = (float*)d_out;

  flownetc_fused_kernel<<<dim3(4096), 256, 0, stream>>>(x1, x2, cw, out);
}

// Round 10
// 58.251 us; speedup vs baseline: 1.4140x; 1.4140x over previous
//
#include <hip/hip_runtime.h>

// FlowNetC fused: f1=conv3x3(x1,w), f2=conv3x3(x2,w),
// out[b,k,h,w] = mean_c f1[b,c,h,w]*f2[b,c,h+dy,w+dx], dy,dx in {-2,0,2}
// B=16,C=3,H=W=512,K=9. f32.
//
// R10 = R5 (known 59us) + conflict-free f2-phase mapping:
//   main 256 f2 units: r=tid>>3, col0=(tid&7)*4  (regular bank pattern,
//   2 rows/quarter-wave at stride 40 words -> 2-way aliasing = free);
//   cleanup 68 units (rows 32-35 x 9 segs + seg 8 of rows 0-31) on tid<68.
// Rest identical to R5: LDS overlay (x1 staging then f2 tile in s_ov),
// 3 barriers, scalar-pipe weights, width-16 global_load_lds staging,
// 1/3 folded into f1, dwordx4 nontemporal stores, XCD swizzle.
// LDS 35.5KB -> 4 blocks/CU.

#define HH 512
#define WW 512
#define TS 32
#define X2R 38
#define X2S 40              // x2 stride, rows 160B-aligned
#define X1R 34
#define X1S 36              // x1 stride, rows 144B-aligned
#define F2R 36
#define F2S 40
#define N2 (3*X2R*X2S)      // 4560 words
#define NF (3*F2R*F2S)      // 4320 words (overlay region size)
#define NC2 (3*X2R*(X2S/4)) // 1140 16B chunks
#define NC1 (3*X1R*(X1S/4)) // 918

typedef const __attribute__((address_space(1))) void* gas_ptr;
typedef __attribute__((address_space(3))) void* las_ptr;
typedef float f32x4 __attribute__((ext_vector_type(4)));

__global__ __launch_bounds__(256)
void flownetc_fused_kernel(const float* __restrict__ x1,
                           const float* __restrict__ x2,
                           const float* __restrict__ cw,
                           float* __restrict__ out) {
  __shared__ __align__(16) float s_x2[N2];
  __shared__ __align__(16) float s_ov[NF];   // x1 staging (first NC1*4) then f2

  const int tid = threadIdx.x;
  // XCD-contiguous swizzle: 4096 blocks / 8 XCDs = 512 contiguous each
  const int bid = blockIdx.x;
  const int f   = (bid & 7) * 512 + (bid >> 3);
  const int ox0 = (f & 15) * TS;
  const int oy0 = ((f >> 4) & 15) * TS;
  const int bi  = f >> 8;

  const float* x2b = x2 + (size_t)bi * 3 * HH * WW;
  const float* x1b = x1 + (size_t)bi * 3 * HH * WW;

  // ---- stage x2 [3][38][40] origin (oy0-3, ox0-3), 16B chunks ----
  for (int q = tid; q < NC2; q += 256) {
    const int colq = q % (X2S / 4);
    const int rp   = q / (X2S / 4);
    const int r    = rp % X2R;
    const int c    = rp / X2R;
    const int gy   = oy0 - 3 + r;
    const int gx0  = ox0 - 3 + colq * 4;
    const float* src = x2b + (size_t)(c * HH + gy) * WW + gx0;
    if ((unsigned)gy < HH && (unsigned)gx0 <= (WW - 4)) {
      __builtin_amdgcn_global_load_lds((gas_ptr)src,
          (las_ptr)(s_x2 + ((q & ~63) << 2)), 16, 0, 0);
    } else {
      const bool rowok = (unsigned)gy < HH;
      float4 v;
      v.x = (rowok && (unsigned)(gx0 + 0) < WW) ? src[0] : 0.f;
      v.y = (rowok && (unsigned)(gx0 + 1) < WW) ? src[1] : 0.f;
      v.z = (rowok && (unsigned)(gx0 + 2) < WW) ? src[2] : 0.f;
      v.w = (rowok && (unsigned)(gx0 + 3) < WW) ? src[3] : 0.f;
      *reinterpret_cast<float4*>(&s_x2[q * 4]) = v;
    }
  }
  // ---- stage x1 [3][34][36] origin (oy0-1, ox0-1) into s_ov ----
  for (int q = tid; q < NC1; q += 256) {
    const int colq = q % (X1S / 4);
    const int rp   = q / (X1S / 4);
    const int r    = rp % X1R;
    const int c    = rp / X1R;
    const int gy   = oy0 - 1 + r;
    const int gx0  = ox0 - 1 + colq * 4;
    const float* src = x1b + (size_t)(c * HH + gy) * WW + gx0;
    if ((unsigned)gy < HH && (unsigned)gx0 <= (WW - 4)) {
      __builtin_amdgcn_global_load_lds((gas_ptr)src,
          (las_ptr)(s_ov + ((q & ~63) << 2)), 16, 0, 0);
    } else {
      const bool rowok = (unsigned)gy < HH;
      float4 v;
      v.x = (rowok && (unsigned)(gx0 + 0) < WW) ? src[0] : 0.f;
      v.y = (rowok && (unsigned)(gx0 + 1) < WW) ? src[1] : 0.f;
      v.z = (rowok && (unsigned)(gx0 + 2) < WW) ? src[2] : 0.f;
      v.w = (rowok && (unsigned)(gx0 + 3) < WW) ? src[3] : 0.f;
      *reinterpret_cast<float4*>(&s_ov[q * 4]) = v;
    }
  }
  __syncthreads();   // staging complete

  // ---- phase B: f2 (regs) from s_x2, f1 (regs) from s_ov-as-x1 ----
  auto f2unit = [&](int r, int col0, float acc[3][4]) {
    #pragma unroll
    for (int co = 0; co < 3; ++co)
      #pragma unroll
      for (int j = 0; j < 4; ++j) acc[co][j] = 0.f;
    #pragma unroll
    for (int ci = 0; ci < 3; ++ci) {
      float win[3][6];
      #pragma unroll
      for (int ky = 0; ky < 3; ++ky) {
        const float* base = &s_x2[(ci * X2R + r + ky) * X2S + col0];
        const float4 a  = *reinterpret_cast<const float4*>(base);
        const float2 b2 = *reinterpret_cast<const float2*>(base + 4);
        win[ky][0] = a.x; win[ky][1] = a.y; win[ky][2] = a.z; win[ky][3] = a.w;
        win[ky][4] = b2.x; win[ky][5] = b2.y;
      }
      #pragma unroll
      for (int co = 0; co < 3; ++co)
        #pragma unroll
        for (int ky = 0; ky < 3; ++ky)
          #pragma unroll
          for (int kx = 0; kx < 3; ++kx) {
            const float w = cw[((co * 3 + ci) * 3 + ky) * 3 + kx]; // uniform -> SGPR
            #pragma unroll
            for (int j = 0; j < 4; ++j)
              acc[co][j] += w * win[ky][j + kx];
          }
    }
    // correlation zero-pads f2: zero outside the image
    const int gy = oy0 - 2 + r;
    #pragma unroll
    for (int j = 0; j < 4; ++j) {
      const int gx = ox0 - 2 + col0 + j;
      if (!((unsigned)gy < HH && (unsigned)gx < WW)) {
        acc[0][j] = 0.f; acc[1][j] = 0.f; acc[2][j] = 0.f;
      }
    }
  };

  // main 256 units: conflict-free regular mapping
  const int r0   = tid >> 3;          // 0..31
  const int c0   = (tid & 7) << 2;    // 0..28
  float acc0[3][4];
  f2unit(r0, c0, acc0);
  // cleanup 68 units: rows 32-35 x 9 segs (36) + seg 8 of rows 0-31 (32)
  float acc1[3][4];
  int r1 = 0, c1 = 0;
  if (tid < 68) {
    if (tid < 36) { r1 = 32 + tid / 9; c1 = (tid % 9) * 4; }
    else          { r1 = tid - 36;     c1 = 32; }
    f2unit(r1, c1, acc1);
  }

  // f1 for run of 4: row py, cols px0..px0+3
  const int py  = tid >> 3;
  const int px0 = (tid & 7) << 2;
  float f1r[3][4] = {};
  #pragma unroll
  for (int ci = 0; ci < 3; ++ci) {
    float win[3][6];
    #pragma unroll
    for (int ky = 0; ky < 3; ++ky) {
      const float* base = &s_ov[(ci * X1R + py + ky) * X1S + px0];
      const float4 a  = *reinterpret_cast<const float4*>(base);
      const float2 b2 = *reinterpret_cast<const float2*>(base + 4);
      win[ky][0] = a.x; win[ky][1] = a.y; win[ky][2] = a.z; win[ky][3] = a.w;
      win[ky][4] = b2.x; win[ky][5] = b2.y;
    }
    #pragma unroll
    for (int co = 0; co < 3; ++co)
      #pragma unroll
      for (int ky = 0; ky < 3; ++ky)
        #pragma unroll
        for (int kx = 0; kx < 3; ++kx) {
          const float w = cw[((co * 3 + ci) * 3 + ky) * 3 + kx];
          #pragma unroll
          for (int j = 0; j < 4; ++j)
            f1r[co][j] += w * win[ky][j + kx];
        }
  }
  #pragma unroll
  for (int co = 0; co < 3; ++co)
    #pragma unroll
    for (int j = 0; j < 4; ++j)
      f1r[co][j] *= (1.f / 3.f);     // fold mean divisor
  __syncthreads();   // all reads of s_ov-as-x1 / s_x2 done

  // ---- phase C: write f2 regs into s_ov overlay ----
  #pragma unroll
  for (int co = 0; co < 3; ++co)
    *reinterpret_cast<float4*>(&s_ov[(co * F2R + r0) * F2S + c0]) =
        make_float4(acc0[co][0], acc0[co][1], acc0[co][2], acc0[co][3]);
  if (tid < 68) {
    #pragma unroll
    for (int co = 0; co < 3; ++co)
      *reinterpret_cast<float4*>(&s_ov[(co * F2R + r1) * F2S + c1]) =
          make_float4(acc1[co][0], acc1[co][1], acc1[co][2], acc1[co][3]);
  }
  __syncthreads();   // f2 tile ready

  // ---- correlation + nontemporal dwordx4 stores ----
  float* outp = out + ((size_t)bi * 9 * HH + (oy0 + py)) * WW + ox0 + px0;
  #pragma unroll
  for (int dyi = 0; dyi < 3; ++dyi) {
    float rv[3][8];
    #pragma unroll
    for (int c = 0; c < 3; ++c) {
      const float* base = &s_ov[(c * F2R + py + dyi * 2) * F2S + px0];
      const float4 a = *reinterpret_cast<const float4*>(base);
      const float4 b = *reinterpret_cast<const float4*>(base + 4);
      rv[c][0] = a.x; rv[c][1] = a.y; rv[c][2] = a.z; rv[c][3] = a.w;
      rv[c][4] = b.x; rv[c][5] = b.y; rv[c][6] = b.z; rv[c][7] = b.w;
    }
    #pragma unroll
    for (int dxi = 0; dxi < 3; ++dxi) {
      const int s = dxi * 2;
      f32x4 o;
      o.x = f1r[0][0]*rv[0][s+0] + f1r[1][0]*rv[1][s+0] + f1r[2][0]*rv[2][s+0];
      o.y = f1r[0][1]*rv[0][s+1] + f1r[1][1]*rv[1][s+1] + f1r[2][1]*rv[2][s+1];
      o.z = f1r[0][2]*rv[0][s+2] + f1r[1][2]*rv[1][s+2] + f1r[2][2]*rv[2][s+2];
      o.w = f1r[0][3]*rv[0][s+3] + f1r[1][3]*rv[1][s+3] + f1r[2][3]*rv[2][s+3];
      __builtin_nontemporal_store(o,
          reinterpret_cast<f32x4*>(outp + (size_t)(dyi * 3 + dxi) * HH * WW));
    }
  }
}

extern "C" void kernel_launch(void* const* d_in, const int* in_sizes, int n_in,
                              void* d_out, int out_size, void* d_ws, size_t ws_size,
                              hipStream_t stream) {
  const float* x1 = (const float*)d_in[0];
  const float* x2 = (const float*)d_in[1];
  const float* cw = (const float*)d_in[2];
  float* out = (float*)d_out;

  flownetc_fused_kernel<<<dim3(4096), 256, 0, stream>>>(x1, x2, cw, out);
}